// Round 18
// baseline (181.243 us; speedup 1.0000x reference)
//
#include <hip/hip_runtime.h>
#include <hip/hip_bf16.h>
#include <stdint.h>

typedef __attribute__((ext_vector_type(4))) float f32x4;
typedef __attribute__((ext_vector_type(8))) short bf16x8;
typedef __attribute__((ext_vector_type(2))) _Float16 f16x2;   // for fdot2 operands
typedef __attribute__((ext_vector_type(2))) __fp16 fp16x2;    // cvt_pkrtz result type
typedef unsigned short u16;

__device__ __forceinline__ u16 f2bf(float f) {
  union { float f; uint32_t u; } v; v.f = f;
  uint32_t r = (v.u + 0x7FFFu + ((v.u >> 16) & 1u)) >> 16;
  return (u16)r;
}
__device__ __forceinline__ float bf2f(u16 u) {
  union { uint32_t i; float f; } v; v.i = ((uint32_t)u) << 16; return v.f;
}
__device__ __forceinline__ float bitsf(uint32_t u) {
  union { uint32_t i; float f; } v; v.i = u; return v.f;
}

// ---- prep: weights (kron sums, x4 vectorized), M2' scaled f32 + f16x2 --------
__global__ __launch_bounds__(256) void prep_kernel(
    const float* __restrict__ x, const float* __restrict__ Aq, const float* __restrict__ Sq,
    const float* __restrict__ Ap, const float* __restrict__ Sp,
    const float* __restrict__ Wsup, const float* __restrict__ Eent,
    u16* __restrict__ xb, u16* __restrict__ wqkv, u16* __restrict__ wproj,
    float* __restrict__ m2, uint32_t* __restrict__ m2h)
{
  uint32_t id = blockIdx.x * 256u + threadIdx.x;
  if (id < 786432u) {              // x convert, 4 floats/thread
    float4 v = ((const float4*)x)[id];
    u16 o[4] = {f2bf(v.x), f2bf(v.y), f2bf(v.z), f2bf(v.w)};
    ((uint2*)xb)[id] = *(uint2*)o;
    return;
  }
  id -= 786432u;
  if (id < 442368u) {              // W_qkv [2304][768], 4 cols/thread
    uint32_t r = id / 192u, c4 = id % 192u, col = c4 * 4u;
    uint32_t a = r / 768u, cc = r % 768u, bb = col >> 8, d = col & 255u;
    float acc[4] = {};
    #pragma unroll
    for (int i = 0; i < 3; ++i) {
      float co = Aq[i*9 + a*3 + bb];
      float4 s = *(const float4*)(Sq + (size_t)i*196608u + cc*256u + d);
      acc[0] += co * s.x; acc[1] += co * s.y; acc[2] += co * s.z; acc[3] += co * s.w;
    }
    u16 o[4] = {f2bf(acc[0]), f2bf(acc[1]), f2bf(acc[2]), f2bf(acc[3])};
    ((uint2*)wqkv)[id] = *(uint2*)o;
    return;
  }
  id -= 442368u;
  if (id < 147456u) {              // W_proj [768][768], 4 cols/thread
    uint32_t r = id / 192u, c4 = id % 192u, col = c4 * 4u;
    uint32_t a = r >> 8, cc = r & 255u, bb = col >> 8, d = col & 255u;
    float acc[4] = {};
    #pragma unroll
    for (int i = 0; i < 3; ++i) {
      float co = Ap[i*9 + a*3 + bb];
      float4 s = *(const float4*)(Sp + (size_t)i*65536u + cc*256u + d);
      acc[0] += co * s.x; acc[1] += co * s.y; acc[2] += co * s.z; acc[3] += co * s.w;
    }
    u16 o[4] = {f2bf(acc[0]), f2bf(acc[1]), f2bf(acc[2]), f2bf(acc[3])};
    ((uint2*)wproj)[id] = *(uint2*)o;
    return;
  }
  id -= 147456u;
  if (id < 144u) {                 // M2'[h][j] = 0.125*2*log2(e)*(Wsup + E@Wsup)
    uint32_t h = id / 12u, j = id % 12u;
    float m = Wsup[h*12 + j];
    for (int tt = 0; tt < 12; ++tt) m += Eent[h*12 + tt] * Wsup[tt*12 + j];
    m2[id] = m * 0.36067376022224085f;   // 0.125 * 2*log2(e)
    return;
  }
  id -= 144u;
  if (id < 72u) {                  // M2' as f16 pairs: m2h[h*6+j2] = (j=2j2, 2j2+1)
    uint32_t h = id / 6u, j2 = id % 6u;
    float v0 = Wsup[h*12 + 2*j2], v1 = Wsup[h*12 + 2*j2 + 1];
    for (int tt = 0; tt < 12; ++tt) {
      v0 += Eent[h*12 + tt] * Wsup[tt*12 + 2*j2];
      v1 += Eent[h*12 + tt] * Wsup[tt*12 + 2*j2 + 1];
    }
    fp16x2 pk = __builtin_amdgcn_cvt_pkrtz(v0 * 0.36067376022224085f,
                                           v1 * 0.36067376022224085f);
    m2h[id] = __builtin_bit_cast(uint32_t, pk);
  }
}

// ---- GEMM: C[M][N] = A[M][K](bf16) * Bt[N][K](bf16)^T + bias -----------------
// FUSEV: columns >= 1536 (V part of qkv) are written in vT2 layout instead of C
// (the branch is block-uniform since bn is a multiple of 128).
template<bool BF16OUT, bool FUSEV>
__global__ __launch_bounds__(256) void gemm_bt(
    const u16* __restrict__ A, const u16* __restrict__ Bt,
    const float* __restrict__ bias, void* __restrict__ Cp,
    u16* __restrict__ vt2,
    int M, int N, int K)
{
  __shared__ __align__(16) u16 As[128*64];
  __shared__ __align__(16) u16 Bs[128*64];
  const int t = threadIdx.x;
  const int wave = t >> 6, lane = t & 63;
  const int l15 = lane & 15, l4 = lane >> 4;
  const int bm = blockIdx.x * 128, bn = blockIdx.y * 128;
  const int wm = (wave >> 1) * 64, wn = (wave & 1) * 64;
  f32x4 acc[4][4] = {};

  for (int k0 = 0; k0 < K; k0 += 64) {
    __syncthreads();
    #pragma unroll
    for (int ro = 0; ro < 4; ++ro) {
      int L = ro*256 + wave*64 + lane;
      int row = L >> 3, cp = L & 7;
      int cl = cp ^ (row & 7);            // XOR swizzle (pre-swizzled source)
      const u16* sa = A + (size_t)(bm + row)*K + k0 + cl*8;
      __builtin_amdgcn_global_load_lds(
        (const __attribute__((address_space(1))) uint32_t*)sa,
        (__attribute__((address_space(3))) uint32_t*)(As + (ro*256 + wave*64)*8), 16, 0, 0);
      const u16* sb = Bt + (size_t)(bn + row)*K + k0 + cl*8;
      __builtin_amdgcn_global_load_lds(
        (const __attribute__((address_space(1))) uint32_t*)sb,
        (__attribute__((address_space(3))) uint32_t*)(Bs + (ro*256 + wave*64)*8), 16, 0, 0);
    }
    asm volatile("s_waitcnt vmcnt(0)" ::: "memory");
    __syncthreads();
    #pragma unroll
    for (int kh = 0; kh < 2; ++kh) {
      bf16x8 af[4], bfr[4];
      #pragma unroll
      for (int mi = 0; mi < 4; ++mi) {
        int row = wm + mi*16 + l15;
        int ch = (kh*4 + l4) ^ (row & 7);
        af[mi] = *(const bf16x8*)(As + row*64 + ch*8);
      }
      #pragma unroll
      for (int ni = 0; ni < 4; ++ni) {
        int row = wn + ni*16 + l15;
        int ch = (kh*4 + l4) ^ (row & 7);
        bfr[ni] = *(const bf16x8*)(Bs + row*64 + ch*8);
      }
      #pragma unroll
      for (int mi = 0; mi < 4; ++mi)
        #pragma unroll
        for (int ni = 0; ni < 4; ++ni)
          acc[mi][ni] = __builtin_amdgcn_mfma_f32_16x16x32_bf16(af[mi], bfr[ni], acc[mi][ni], 0, 0, 0);
    }
  }
  #pragma unroll
  for (int mi = 0; mi < 4; ++mi) {
    #pragma unroll
    for (int ni = 0; ni < 4; ++ni) {
      int col = bn + wn + ni*16 + l15;
      float bv = bias[col];
      #pragma unroll
      for (int r = 0; r < 4; ++r) {
        int rowg = bm + wm + mi*16 + l4*4 + r;
        float v = acc[mi][ni][r] + bv;
        if (FUSEV && col >= 1536) {        // V part -> vT2[b][n/8][d][n&7]
          int d = col - 1536;
          vt2[((size_t)((rowg >> 10)*128 + ((rowg & 1023) >> 3)))*6144 + d*8 + (rowg & 7)] = f2bf(v);
        } else if (BF16OUT) {
          ((u16*)Cp)[(size_t)rowg*N + col] = f2bf(v);
        } else {
          ((float*)Cp)[(size_t)rowg*N + col] = v;
        }
      }
    }
  }
}

// ---- fused attention: 32m/wave (r3 shape) + f16-packed scores (r10) ----------
// Wave handles 32 m per sit (sit = 128 m, 4 sits at MS=2): barriers halve and
// each interval holds 2x independent K-loads/MFMAs for the scheduler. Scores
// f16-packed: sp[6][2][4] = 48 VGPR (r3's f32 version needed 96 and spilled).
// Ps/PV indexing is r3's verified 4-chunk layout; denominator = r12's P-sum.
template<int MS>
__global__ __launch_bounds__(256, 2) void attn_kernel(
    const u16* __restrict__ qkv, const u16* __restrict__ vT2,
    const uint32_t* __restrict__ M2h, u16* __restrict__ outp, float* __restrict__ Lpart)
{
  __shared__ __align__(16) u16 Qs[16*768];      // [q16][chunk96*8] XOR-swizzled
  __shared__ __align__(16) u16 Ps[4*12*16*32];  // [ch4][h12][q16][m32] swizzled 16B

  const int t = threadIdx.x;
  const int wave = t >> 6, lane = t & 63;
  const int l15 = lane & 15, l4 = lane >> 4;

  const int G = MS * 4;
  const int fid = blockIdx.x;
  const int g = fid % G, qt = fid / G;          // XCD = fid%8 (G mult of 4)
  const int b = g & 3, ms = g >> 2;
  const int q0 = qt * 16;
  const int mbeg = ms * (1024 / MS);

  #pragma unroll
  for (int i = 0; i < 6; ++i) {                 // stage Q (16x768), swizzled src
    int T = i*256 + t;
    int r = T / 96, c = T % 96;
    int cs = c ^ (r & 7);
    const u16* src = qkv + (size_t)(b*1024 + q0 + r)*2304 + cs*8;
    __builtin_amdgcn_global_load_lds(
      (const __attribute__((address_space(1))) uint32_t*)src,
      (__attribute__((address_space(3))) uint32_t*)(Qs + T*8), 16, 0, 0);
  }
  asm volatile("s_waitcnt vmcnt(0)" ::: "memory");
  __syncthreads();                              // Q staged

  const float C1 = -2.8853900817779268f;        // -2*log2(e)
  const float C2 =  1.4426950408889634f;        //  log2(e)
  f32x4 oacc[3][4] = {};
  float ps_sum[3] = {0.f, 0.f, 0.f};            // per-lane partial of l

  for (int sit = 0; sit < (1024/MS)/128; ++sit) {
    const int mb0 = mbeg + sit*128;
    const int mb = mb0 + wave*32;               // this wave's 32-m chunk

    // ---- QK^T per head-pair x 2 m-halves; pack scores to f16x2 -------------
    uint32_t sp[6][2][4];                       // [h2][mh][r], 48 VGPR
    const u16* krow0 = qkv + (size_t)(b*1024 + mb + l15)*2304 + 768 + l4*8;
    const u16* krow1 = qkv + (size_t)(b*1024 + mb + 16 + l15)*2304 + 768 + l4*8;
    #pragma unroll
    for (int h2 = 0; h2 < 6; ++h2) {
      f32x4 s0[2], s1[2];
      {
        int h = 2*h2;
        bf16x8 qa = *(const bf16x8*)(Qs + l15*768 + ((h*8 + l4) ^ (l15 & 7))*8);
        bf16x8 qb = *(const bf16x8*)(Qs + l15*768 + ((h*8 + 4 + l4) ^ (l15 & 7))*8);
        f32x4 z0 = {}, z1 = {};
        z0 = __builtin_amdgcn_mfma_f32_16x16x32_bf16(qa, *(const bf16x8*)(krow0 + h*64), z0, 0, 0, 0);
        s0[0] = __builtin_amdgcn_mfma_f32_16x16x32_bf16(qb, *(const bf16x8*)(krow0 + h*64 + 32), z0, 0, 0, 0);
        z1 = __builtin_amdgcn_mfma_f32_16x16x32_bf16(qa, *(const bf16x8*)(krow1 + h*64), z1, 0, 0, 0);
        s0[1] = __builtin_amdgcn_mfma_f32_16x16x32_bf16(qb, *(const bf16x8*)(krow1 + h*64 + 32), z1, 0, 0, 0);
      }
      {
        int h = 2*h2 + 1;
        bf16x8 qa = *(const bf16x8*)(Qs + l15*768 + ((h*8 + l4) ^ (l15 & 7))*8);
        bf16x8 qb = *(const bf16x8*)(Qs + l15*768 + ((h*8 + 4 + l4) ^ (l15 & 7))*8);
        f32x4 z0 = {}, z1 = {};
        z0 = __builtin_amdgcn_mfma_f32_16x16x32_bf16(qa, *(const bf16x8*)(krow0 + h*64), z0, 0, 0, 0);
        s1[0] = __builtin_amdgcn_mfma_f32_16x16x32_bf16(qb, *(const bf16x8*)(krow0 + h*64 + 32), z0, 0, 0, 0);
        z1 = __builtin_amdgcn_mfma_f32_16x16x32_bf16(qa, *(const bf16x8*)(krow1 + h*64), z1, 0, 0, 0);
        s1[1] = __builtin_amdgcn_mfma_f32_16x16x32_bf16(qb, *(const bf16x8*)(krow1 + h*64 + 32), z1, 0, 0, 0);
      }
      #pragma unroll
      for (int mh = 0; mh < 2; ++mh)
        #pragma unroll
        for (int r = 0; r < 4; ++r) {
          fp16x2 pk = __builtin_amdgcn_cvt_pkrtz(s0[mh][r], s1[mh][r]);
          sp[h2][mh][r] = __builtin_bit_cast(uint32_t, pk);
        }
    }

    // ---- head-mix via dot2 + exp2 chain; write P to LDS (r3 indexing) ------
    #pragma unroll
    for (int h = 0; h < 12; ++h) {
      const uint32_t* mrow = M2h + h*6;
      #pragma unroll
      for (int mh = 0; mh < 2; ++mh)
        #pragma unroll
        for (int r = 0; r < 4; ++r) {
          float e = 0.f;
          #pragma unroll
          for (int j2 = 0; j2 < 6; ++j2)
            e = __builtin_amdgcn_fdot2(__builtin_bit_cast(f16x2, sp[j2][mh][r]),
                                       __builtin_bit_cast(f16x2, mrow[j2]),
                                       e, false);
          float ex = __builtin_amdgcn_exp2f(e);          // = exp(2*sup_mix)
          float tv = __builtin_amdgcn_rcpf(ex + 1.f);    // inf-safe
          float p  = __builtin_amdgcn_exp2f(fmaf(C1, tv, C2));  // exp(tanh)
          int q = l4*4 + r;
          int c = (mh*2 + (l15 >> 3)) ^ (q & 3);         // 16B-chunk swizzle
          Ps[((wave*12 + h)*16 + q)*32 + c*8 + (l15 & 7)] = f2bf(p);
        }
    }
    __syncthreads();                             // B1: all P chunks visible

    // ---- PV: 3 heads/wave over 4 chunks (128 m); l from pf bf16 sums -------
    #pragma unroll
    for (int hh = 0; hh < 3; ++hh) {
      int h = wave*3 + hh;
      #pragma unroll
      for (int ch = 0; ch < 4; ++ch) {
        bf16x8 pf = *(const bf16x8*)(Ps + ((ch*12 + h)*16 + l15)*32 + ((l4 ^ (l15 & 3))*8));
        {                                        // l partial: sum 8 bf16 of pf
          union { bf16x8 v; uint32_t u[4]; } pc; pc.v = pf;
          float s = 0.f;
          #pragma unroll
          for (int k = 0; k < 4; ++k)
            s += bitsf(pc.u[k] & 0xFFFF0000u) + bitsf(pc.u[k] << 16);
          ps_sum[hh] += s;
        }
        const u16* vb = vT2 + (size_t)(b*128 + (mb0 >> 3) + ch*4 + l4)*6144 + (size_t)(h*64)*8;
        #pragma unroll
        for (int ci = 0; ci < 4; ++ci) {
          bf16x8 vf = *(const bf16x8*)(vb + (ci*16 + l15)*8);
          oacc[hh][ci] = __builtin_amdgcn_mfma_f32_16x16x32_bf16(pf, vf, oacc[hh][ci], 0, 0, 0);
        }
      }
    }
    __syncthreads();                             // B2: PV done before next P write
  }

  // ---- complete row-sums: lanes {l15, l15+16, l15+32, l15+48} hold partials -
  #pragma unroll
  for (int hh = 0; hh < 3; ++hh) {
    ps_sum[hh] += __shfl_xor(ps_sum[hh], 16);
    ps_sum[hh] += __shfl_xor(ps_sum[hh], 32);    // now full l for q=l15
  }

  if (MS == 1) {
    float* Lsf = (float*)Ps;                     // Ps dead after last B2
    if (l4 == 0)
      #pragma unroll
      for (int hh = 0; hh < 3; ++hh) Lsf[(wave*3 + hh)*16 + l15] = ps_sum[hh];
    __syncthreads();
    #pragma unroll
    for (int hh = 0; hh < 3; ++hh) {
      int h = wave*3 + hh;
      #pragma unroll
      for (int r = 0; r < 4; ++r) {
        int q = l4*4 + r;
        float linv = __builtin_amdgcn_rcpf(Lsf[h*16 + q]);
        #pragma unroll
        for (int ci = 0; ci < 4; ++ci)
          outp[(size_t)(b*1024 + q0 + q)*768 + h*64 + ci*16 + l15] = f2bf(oacc[hh][ci][r] * linv);
      }
    }
  } else {
    #pragma unroll
    for (int hh = 0; hh < 3; ++hh) {
      int h = wave*3 + hh;
      #pragma unroll
      for (int r = 0; r < 4; ++r) {
        int q = l4*4 + r;
        #pragma unroll
        for (int ci = 0; ci < 4; ++ci)
          outp[((size_t)(ms*4 + b)*1024 + q0 + q)*768 + h*64 + ci*16 + l15] = f2bf(oacc[hh][ci][r]);
      }
      if (l4 == 0)
        Lpart[((ms*4 + b)*12 + h)*1024 + q0 + l15] = ps_sum[hh];
    }
  }
}

// ---------------- merge partials: aout = sum O / sum l -----------------------
template<int MS>
__global__ __launch_bounds__(256) void merge_kernel(
    const u16* __restrict__ Opart, const float* __restrict__ Lpart, u16* __restrict__ aout)
{
  const uint32_t idx = blockIdx.x * 256u + threadIdx.x;   // 393216 threads x 8 bf16
  const uint32_t flat = idx * 8u;
  const uint32_t b = flat / 786432u, r0 = flat % 786432u;
  const uint32_t n = r0 / 768u, c = r0 % 768u, h = c >> 6;
  float acc[8] = {};
  float l = 0.f;
  #pragma unroll
  for (int msi = 0; msi < MS; ++msi) {
    uint4 v = *(const uint4*)(Opart + ((size_t)((msi*4u + b)*1024u + n))*768u + c);
    const u16* pv = (const u16*)&v;
    #pragma unroll
    for (int k = 0; k < 8; ++k) acc[k] += bf2f(pv[k]);
    l += Lpart[((msi*4u + b)*12u + h)*1024u + n];
  }
  float linv = __builtin_amdgcn_rcpf(l);
  u16 o[8];
  #pragma unroll
  for (int k = 0; k < 8; ++k) o[k] = f2bf(acc[k] * linv);
  *(uint4*)(aout + flat) = *(uint4*)o;
}

// ---------------- launch ------------------------------------------------------
extern "C" void kernel_launch(void* const* d_in, const int* in_sizes, int n_in,
                              void* d_out, int out_size, void* d_ws, size_t ws_size,
                              hipStream_t stream)
{
  const float* x    = (const float*)d_in[0];
  const float* Aq   = (const float*)d_in[1];
  const float* Sq   = (const float*)d_in[2];
  const float* bq   = (const float*)d_in[3];
  const float* Ap   = (const float*)d_in[4];
  const float* Sp   = (const float*)d_in[5];
  const float* bp   = (const float*)d_in[6];
  const float* Wsup = (const float*)d_in[7];
  const float* Eent = (const float*)d_in[8];

  char* ws = (char*)d_ws;
  u16*  xb    = (u16*)(ws);                  //  6,291,456 B  x bf16
  u16*  wqkv  = (u16*)(ws + 6291456);        //  3,538,944 B  [2304][768]
  u16*  wproj = (u16*)(ws + 9830400);        //  1,179,648 B  [768][768]
  u16*  qkvb  = (u16*)(ws + 11010048);       // 18,874,368 B  [4096][2304] (V third unused)
  u16*  vT2   = (u16*)(ws + 29884416);       //  6,291,456 B  [4][128][768][8]
  u16*  aout  = (u16*)(ws + 36175872);       //  6,291,456 B  [4096][768]
  float* m2   = (float*)(ws + 42467328);     //        576 B
  uint32_t* m2h = (uint32_t*)(ws + 42467904);//        288 B  f16-pair M2
  const size_t base = 42468224;              // end of fixed region (64B aligned)

  // MS=2: merge traffic halves, 512 attn blocks = one co-residency round,
  // XCD map g = fid%8 exact.
  const int MS = (ws_size >= base + 2*6488064u) ? 2 : 1;
  float* Lpart = (float*)(ws + base);                        // MS*196608 B
  u16*   Opart = (u16*)(ws + base + (size_t)MS*196608u);     // MS*6291456 B

  prep_kernel<<<5377, 256, 0, stream>>>(x, Aq, Sq, Ap, Sp, Wsup, Eent, xb, wqkv, wproj, m2, m2h);
  gemm_bt<true, true><<<dim3(32, 18), 256, 0, stream>>>(xb, wqkv, bq, qkvb, vT2, 4096, 2304, 768);
  if (MS == 2) {
    attn_kernel<2><<<512, 256, 0, stream>>>(qkvb, vT2, m2h, Opart, Lpart);
    merge_kernel<2><<<1536, 256, 0, stream>>>(Opart, Lpart, aout);
  } else {
    attn_kernel<1><<<256, 256, 0, stream>>>(qkvb, vT2, m2h, aout, nullptr);
  }
  gemm_bt<false, false><<<dim3(32, 6), 256, 0, stream>>>(aout, wproj, bp, (float*)d_out, nullptr, 4096, 768, 768);
}

// Round 19
// 137.764 us; speedup vs baseline: 1.3156x; 1.3156x over previous
//
#include <hip/hip_runtime.h>
#include <hip/hip_bf16.h>
#include <stdint.h>

typedef __attribute__((ext_vector_type(4))) float f32x4;
typedef __attribute__((ext_vector_type(8))) short bf16x8;
typedef __attribute__((ext_vector_type(2))) _Float16 f16x2;   // for fdot2 operands
typedef __attribute__((ext_vector_type(2))) __fp16 fp16x2;    // cvt_pkrtz result type
typedef unsigned short u16;

__device__ __forceinline__ u16 f2bf(float f) {
  union { float f; uint32_t u; } v; v.f = f;
  uint32_t r = (v.u + 0x7FFFu + ((v.u >> 16) & 1u)) >> 16;
  return (u16)r;
}
__device__ __forceinline__ float bf2f(u16 u) {
  union { uint32_t i; float f; } v; v.i = ((uint32_t)u) << 16; return v.f;
}
__device__ __forceinline__ float bitsf(uint32_t u) {
  union { uint32_t i; float f; } v; v.i = u; return v.f;
}

// ---- prep: weights (kron sums, x4 vectorized), M2' scaled f32 + f16x2 --------
__global__ __launch_bounds__(256) void prep_kernel(
    const float* __restrict__ x, const float* __restrict__ Aq, const float* __restrict__ Sq,
    const float* __restrict__ Ap, const float* __restrict__ Sp,
    const float* __restrict__ Wsup, const float* __restrict__ Eent,
    u16* __restrict__ xb, u16* __restrict__ wqkv, u16* __restrict__ wproj,
    float* __restrict__ m2, uint32_t* __restrict__ m2h)
{
  uint32_t id = blockIdx.x * 256u + threadIdx.x;
  if (id < 786432u) {              // x convert, 4 floats/thread
    float4 v = ((const float4*)x)[id];
    u16 o[4] = {f2bf(v.x), f2bf(v.y), f2bf(v.z), f2bf(v.w)};
    ((uint2*)xb)[id] = *(uint2*)o;
    return;
  }
  id -= 786432u;
  if (id < 442368u) {              // W_qkv [2304][768], 4 cols/thread
    uint32_t r = id / 192u, c4 = id % 192u, col = c4 * 4u;
    uint32_t a = r / 768u, cc = r % 768u, bb = col >> 8, d = col & 255u;
    float acc[4] = {};
    #pragma unroll
    for (int i = 0; i < 3; ++i) {
      float co = Aq[i*9 + a*3 + bb];
      float4 s = *(const float4*)(Sq + (size_t)i*196608u + cc*256u + d);
      acc[0] += co * s.x; acc[1] += co * s.y; acc[2] += co * s.z; acc[3] += co * s.w;
    }
    u16 o[4] = {f2bf(acc[0]), f2bf(acc[1]), f2bf(acc[2]), f2bf(acc[3])};
    ((uint2*)wqkv)[id] = *(uint2*)o;
    return;
  }
  id -= 442368u;
  if (id < 147456u) {              // W_proj [768][768], 4 cols/thread
    uint32_t r = id / 192u, c4 = id % 192u, col = c4 * 4u;
    uint32_t a = r >> 8, cc = r & 255u, bb = col >> 8, d = col & 255u;
    float acc[4] = {};
    #pragma unroll
    for (int i = 0; i < 3; ++i) {
      float co = Ap[i*9 + a*3 + bb];
      float4 s = *(const float4*)(Sp + (size_t)i*65536u + cc*256u + d);
      acc[0] += co * s.x; acc[1] += co * s.y; acc[2] += co * s.z; acc[3] += co * s.w;
    }
    u16 o[4] = {f2bf(acc[0]), f2bf(acc[1]), f2bf(acc[2]), f2bf(acc[3])};
    ((uint2*)wproj)[id] = *(uint2*)o;
    return;
  }
  id -= 147456u;
  if (id < 144u) {                 // M2'[h][j] = 0.125*2*log2(e)*(Wsup + E@Wsup)
    uint32_t h = id / 12u, j = id % 12u;
    float m = Wsup[h*12 + j];
    for (int tt = 0; tt < 12; ++tt) m += Eent[h*12 + tt] * Wsup[tt*12 + j];
    m2[id] = m * 0.36067376022224085f;   // 0.125 * 2*log2(e)
    return;
  }
  id -= 144u;
  if (id < 72u) {                  // M2' as f16 pairs: m2h[h*6+j2] = (j=2j2, 2j2+1)
    uint32_t h = id / 6u, j2 = id % 6u;
    float v0 = Wsup[h*12 + 2*j2], v1 = Wsup[h*12 + 2*j2 + 1];
    for (int tt = 0; tt < 12; ++tt) {
      v0 += Eent[h*12 + tt] * Wsup[tt*12 + 2*j2];
      v1 += Eent[h*12 + tt] * Wsup[tt*12 + 2*j2 + 1];
    }
    fp16x2 pk = __builtin_amdgcn_cvt_pkrtz(v0 * 0.36067376022224085f,
                                           v1 * 0.36067376022224085f);
    m2h[id] = __builtin_bit_cast(uint32_t, pk);
  }
}

// ---- GEMM: C[M][N] = A[M][K](bf16) * Bt[N][K](bf16)^T + bias -----------------
// FUSEV: columns >= 1536 (V part of qkv) are written in vT2 layout instead of C
// (the branch is block-uniform since bn is a multiple of 128).
template<bool BF16OUT, bool FUSEV>
__global__ __launch_bounds__(256) void gemm_bt(
    const u16* __restrict__ A, const u16* __restrict__ Bt,
    const float* __restrict__ bias, void* __restrict__ Cp,
    u16* __restrict__ vt2,
    int M, int N, int K)
{
  __shared__ __align__(16) u16 As[128*64];
  __shared__ __align__(16) u16 Bs[128*64];
  const int t = threadIdx.x;
  const int wave = t >> 6, lane = t & 63;
  const int l15 = lane & 15, l4 = lane >> 4;
  const int bm = blockIdx.x * 128, bn = blockIdx.y * 128;
  const int wm = (wave >> 1) * 64, wn = (wave & 1) * 64;
  f32x4 acc[4][4] = {};

  for (int k0 = 0; k0 < K; k0 += 64) {
    __syncthreads();
    #pragma unroll
    for (int ro = 0; ro < 4; ++ro) {
      int L = ro*256 + wave*64 + lane;
      int row = L >> 3, cp = L & 7;
      int cl = cp ^ (row & 7);            // XOR swizzle (pre-swizzled source)
      const u16* sa = A + (size_t)(bm + row)*K + k0 + cl*8;
      __builtin_amdgcn_global_load_lds(
        (const __attribute__((address_space(1))) uint32_t*)sa,
        (__attribute__((address_space(3))) uint32_t*)(As + (ro*256 + wave*64)*8), 16, 0, 0);
      const u16* sb = Bt + (size_t)(bn + row)*K + k0 + cl*8;
      __builtin_amdgcn_global_load_lds(
        (const __attribute__((address_space(1))) uint32_t*)sb,
        (__attribute__((address_space(3))) uint32_t*)(Bs + (ro*256 + wave*64)*8), 16, 0, 0);
    }
    asm volatile("s_waitcnt vmcnt(0)" ::: "memory");
    __syncthreads();
    #pragma unroll
    for (int kh = 0; kh < 2; ++kh) {
      bf16x8 af[4], bfr[4];
      #pragma unroll
      for (int mi = 0; mi < 4; ++mi) {
        int row = wm + mi*16 + l15;
        int ch = (kh*4 + l4) ^ (row & 7);
        af[mi] = *(const bf16x8*)(As + row*64 + ch*8);
      }
      #pragma unroll
      for (int ni = 0; ni < 4; ++ni) {
        int row = wn + ni*16 + l15;
        int ch = (kh*4 + l4) ^ (row & 7);
        bfr[ni] = *(const bf16x8*)(Bs + row*64 + ch*8);
      }
      #pragma unroll
      for (int mi = 0; mi < 4; ++mi)
        #pragma unroll
        for (int ni = 0; ni < 4; ++ni)
          acc[mi][ni] = __builtin_amdgcn_mfma_f32_16x16x32_bf16(af[mi], bfr[ni], acc[mi][ni], 0, 0, 0);
    }
  }
  #pragma unroll
  for (int mi = 0; mi < 4; ++mi) {
    #pragma unroll
    for (int ni = 0; ni < 4; ++ni) {
      int col = bn + wn + ni*16 + l15;
      float bv = bias[col];
      #pragma unroll
      for (int r = 0; r < 4; ++r) {
        int rowg = bm + wm + mi*16 + l4*4 + r;
        float v = acc[mi][ni][r] + bv;
        if (FUSEV && col >= 1536) {        // V part -> vT2[b][n/8][d][n&7]
          int d = col - 1536;
          vt2[((size_t)((rowg >> 10)*128 + ((rowg & 1023) >> 3)))*6144 + d*8 + (rowg & 7)] = f2bf(v);
        } else if (BF16OUT) {
          ((u16*)Cp)[(size_t)rowg*N + col] = f2bf(v);
        } else {
          ((float*)Cp)[(size_t)rowg*N + col] = v;
        }
      }
    }
  }
}

// ---------------- fused attention: P-sum denominator (r13 exact body) ---------
template<int MS>
__global__ __launch_bounds__(256, 2) void attn_kernel(
    const u16* __restrict__ qkv, const u16* __restrict__ vT2,
    const uint32_t* __restrict__ M2h, u16* __restrict__ outp, float* __restrict__ Lpart)
{
  __shared__ __align__(16) u16 Qs[16*768];      // [q16][chunk96*8] XOR-swizzled
  __shared__ __align__(16) u16 Ps[2*12*16*32];  // [ch2][h12][q16][m32] swizzled 16B

  const int t = threadIdx.x;
  const int wave = t >> 6, lane = t & 63;
  const int l15 = lane & 15, l4 = lane >> 4;

  const int G = MS * 4;
  const int fid = blockIdx.x;
  const int g = fid % G, qt = fid / G;          // XCD = fid%8 (G mult of 4)
  const int b = g & 3, ms = g >> 2;
  const int q0 = qt * 16;
  const int mbeg = ms * (1024 / MS);

  #pragma unroll
  for (int i = 0; i < 6; ++i) {                 // stage Q (16x768), swizzled src
    int T = i*256 + t;
    int r = T / 96, c = T % 96;
    int cs = c ^ (r & 7);
    const u16* src = qkv + (size_t)(b*1024 + q0 + r)*2304 + cs*8;
    __builtin_amdgcn_global_load_lds(
      (const __attribute__((address_space(1))) uint32_t*)src,
      (__attribute__((address_space(3))) uint32_t*)(Qs + T*8), 16, 0, 0);
  }
  asm volatile("s_waitcnt vmcnt(0)" ::: "memory");
  __syncthreads();                              // Q staged

  const float C1 = -2.8853900817779268f;        // -2*log2(e)
  const float C2 =  1.4426950408889634f;        //  log2(e)
  f32x4 oacc[3][4] = {};
  float ps_sum[3] = {0.f, 0.f, 0.f};            // per-lane partial of l

  for (int sit = 0; sit < (1024/MS)/64; ++sit) {
    const int mb0 = mbeg + sit*64;
    const int mb = mb0 + wave*16;               // this wave's 16-m chunk

    // ---- QK^T per head-pair; pack scores to f16x2 (sp = 24 VGPR) ----
    uint32_t sp[6][4];
    const u16* krow = qkv + (size_t)(b*1024 + mb + l15)*2304 + 768 + l4*8;
    #pragma unroll
    for (int h2 = 0; h2 < 6; ++h2) {
      f32x4 s0, s1;
      {
        int h = 2*h2;
        bf16x8 qa = *(const bf16x8*)(Qs + l15*768 + ((h*8 + l4) ^ (l15 & 7))*8);
        bf16x8 qb = *(const bf16x8*)(Qs + l15*768 + ((h*8 + 4 + l4) ^ (l15 & 7))*8);
        f32x4 z = {};
        z = __builtin_amdgcn_mfma_f32_16x16x32_bf16(qa, *(const bf16x8*)(krow + h*64), z, 0, 0, 0);
        s0 = __builtin_amdgcn_mfma_f32_16x16x32_bf16(qb, *(const bf16x8*)(krow + h*64 + 32), z, 0, 0, 0);
      }
      {
        int h = 2*h2 + 1;
        bf16x8 qa = *(const bf16x8*)(Qs + l15*768 + ((h*8 + l4) ^ (l15 & 7))*8);
        bf16x8 qb = *(const bf16x8*)(Qs + l15*768 + ((h*8 + 4 + l4) ^ (l15 & 7))*8);
        f32x4 z = {};
        z = __builtin_amdgcn_mfma_f32_16x16x32_bf16(qa, *(const bf16x8*)(krow + h*64), z, 0, 0, 0);
        s1 = __builtin_amdgcn_mfma_f32_16x16x32_bf16(qb, *(const bf16x8*)(krow + h*64 + 32), z, 0, 0, 0);
      }
      #pragma unroll
      for (int r = 0; r < 4; ++r) {
        fp16x2 pk = __builtin_amdgcn_cvt_pkrtz(s0[r], s1[r]);
        sp[h2][r] = __builtin_bit_cast(uint32_t, pk);
      }
    }

    // ---- head-mix via dot2 (M2 f16-pairs, uniform -> SGPR) + exp2 chain ----
    #pragma unroll
    for (int h = 0; h < 12; ++h) {
      const uint32_t* mrow = M2h + h*6;
      #pragma unroll
      for (int r = 0; r < 4; ++r) {
        float e = 0.f;
        #pragma unroll
        for (int j2 = 0; j2 < 6; ++j2)
          e = __builtin_amdgcn_fdot2(__builtin_bit_cast(f16x2, sp[j2][r]),
                                     __builtin_bit_cast(f16x2, mrow[j2]),
                                     e, false);
        float ex = __builtin_amdgcn_exp2f(e);          // = exp(2*sup_mix)
        float tv = __builtin_amdgcn_rcpf(ex + 1.f);    // inf-safe
        float p  = __builtin_amdgcn_exp2f(fmaf(C1, tv, C2));  // exp(tanh) in [e^-1,e]
        int q = l4*4 + r;
        int c = ((wave & 1)*2 + (l15 >> 3)) ^ (q & 3);  // 16B-chunk swizzle
        Ps[(((wave >> 1)*12 + h)*16 + q)*32 + c*8 + (l15 & 7)] = f2bf(p);
      }
    }
    __syncthreads();                             // B1: all P chunks visible

    // ---- PV: 3 heads/wave over 2 chunks (64 m); l from pf bf16 sums --------
    #pragma unroll
    for (int hh = 0; hh < 3; ++hh) {
      int h = wave*3 + hh;
      #pragma unroll
      for (int ch = 0; ch < 2; ++ch) {
        bf16x8 pf = *(const bf16x8*)(Ps + ((ch*12 + h)*16 + l15)*32 + ((l4 ^ (l15 & 3))*8));
        {                                        // l partial: sum 8 bf16 of pf
          union { bf16x8 v; uint32_t u[4]; } pc; pc.v = pf;
          float s = 0.f;
          #pragma unroll
          for (int k = 0; k < 4; ++k)
            s += bitsf(pc.u[k] & 0xFFFF0000u) + bitsf(pc.u[k] << 16);
          ps_sum[hh] += s;
        }
        const u16* vb = vT2 + (size_t)(b*128 + (mb0 >> 3) + ch*4 + l4)*6144 + (size_t)(h*64)*8;
        #pragma unroll
        for (int ci = 0; ci < 4; ++ci) {
          bf16x8 vf = *(const bf16x8*)(vb + (ci*16 + l15)*8);
          oacc[hh][ci] = __builtin_amdgcn_mfma_f32_16x16x32_bf16(pf, vf, oacc[hh][ci], 0, 0, 0);
        }
      }
    }
    __syncthreads();                             // B2: PV done before next P write
  }

  // ---- complete row-sums: lanes {l15, l15+16, l15+32, l15+48} hold partials -
  #pragma unroll
  for (int hh = 0; hh < 3; ++hh) {
    ps_sum[hh] += __shfl_xor(ps_sum[hh], 16);
    ps_sum[hh] += __shfl_xor(ps_sum[hh], 32);    // now full l for q=l15
  }

  if (MS == 1) {
    float* Lsf = (float*)Ps;                     // Ps dead after last B2
    if (l4 == 0)
      #pragma unroll
      for (int hh = 0; hh < 3; ++hh) Lsf[(wave*3 + hh)*16 + l15] = ps_sum[hh];
    __syncthreads();
    #pragma unroll
    for (int hh = 0; hh < 3; ++hh) {
      int h = wave*3 + hh;
      #pragma unroll
      for (int r = 0; r < 4; ++r) {
        int q = l4*4 + r;
        float linv = __builtin_amdgcn_rcpf(Lsf[h*16 + q]);
        #pragma unroll
        for (int ci = 0; ci < 4; ++ci)
          outp[(size_t)(b*1024 + q0 + q)*768 + h*64 + ci*16 + l15] = f2bf(oacc[hh][ci][r] * linv);
      }
    }
  } else {
    #pragma unroll
    for (int hh = 0; hh < 3; ++hh) {
      int h = wave*3 + hh;
      #pragma unroll
      for (int r = 0; r < 4; ++r) {
        int q = l4*4 + r;
        #pragma unroll
        for (int ci = 0; ci < 4; ++ci)
          outp[((size_t)(ms*4 + b)*1024 + q0 + q)*768 + h*64 + ci*16 + l15] = f2bf(oacc[hh][ci][r]);
      }
      if (l4 == 0)
        Lpart[((ms*4 + b)*12 + h)*1024 + q0 + l15] = ps_sum[hh];
    }
  }
}

// ---------------- merge partials: aout = sum O / sum l -----------------------
template<int MS>
__global__ __launch_bounds__(256) void merge_kernel(
    const u16* __restrict__ Opart, const float* __restrict__ Lpart, u16* __restrict__ aout)
{
  const uint32_t idx = blockIdx.x * 256u + threadIdx.x;   // 393216 threads x 8 bf16
  const uint32_t flat = idx * 8u;
  const uint32_t b = flat / 786432u, r0 = flat % 786432u;
  const uint32_t n = r0 / 768u, c = r0 % 768u, h = c >> 6;
  float acc[8] = {};
  float l = 0.f;
  #pragma unroll
  for (int msi = 0; msi < MS; ++msi) {
    uint4 v = *(const uint4*)(Opart + ((size_t)((msi*4u + b)*1024u + n))*768u + c);
    const u16* pv = (const u16*)&v;
    #pragma unroll
    for (int k = 0; k < 8; ++k) acc[k] += bf2f(pv[k]);
    l += Lpart[((msi*4u + b)*12u + h)*1024u + n];
  }
  float linv = __builtin_amdgcn_rcpf(l);
  u16 o[8];
  #pragma unroll
  for (int k = 0; k < 8; ++k) o[k] = f2bf(acc[k] * linv);
  *(uint4*)(aout + flat) = *(uint4*)o;
}

// ---------------- launch ------------------------------------------------------
extern "C" void kernel_launch(void* const* d_in, const int* in_sizes, int n_in,
                              void* d_out, int out_size, void* d_ws, size_t ws_size,
                              hipStream_t stream)
{
  const float* x    = (const float*)d_in[0];
  const float* Aq   = (const float*)d_in[1];
  const float* Sq   = (const float*)d_in[2];
  const float* bq   = (const float*)d_in[3];
  const float* Ap   = (const float*)d_in[4];
  const float* Sp   = (const float*)d_in[5];
  const float* bp   = (const float*)d_in[6];
  const float* Wsup = (const float*)d_in[7];
  const float* Eent = (const float*)d_in[8];

  char* ws = (char*)d_ws;
  u16*  xb    = (u16*)(ws);                  //  6,291,456 B  x bf16
  u16*  wqkv  = (u16*)(ws + 6291456);        //  3,538,944 B  [2304][768]
  u16*  wproj = (u16*)(ws + 9830400);        //  1,179,648 B  [768][768]
  u16*  qkvb  = (u16*)(ws + 11010048);       // 18,874,368 B  [4096][2304] (V third unused)
  u16*  vT2   = (u16*)(ws + 29884416);       //  6,291,456 B  [4][128][768][8]
  u16*  aout  = (u16*)(ws + 36175872);       //  6,291,456 B  [4096][768]
  float* m2   = (float*)(ws + 42467328);     //        576 B
  uint32_t* m2h = (uint32_t*)(ws + 42467904);//        288 B  f16-pair M2
  const size_t base = 42468224;              // end of fixed region (64B aligned)

  // MS=2 (isolated from r14's dbuf): merge traffic halves, 512 attn blocks =
  // exactly one co-residency round (2 blocks/CU), XCD map g = fid%8 exact.
  const int MS = (ws_size >= base + 2*6488064u) ? 2 : 1;
  float* Lpart = (float*)(ws + base);                        // MS*196608 B
  u16*   Opart = (u16*)(ws + base + (size_t)MS*196608u);     // MS*6291456 B

  prep_kernel<<<5377, 256, 0, stream>>>(x, Aq, Sq, Ap, Sp, Wsup, Eent, xb, wqkv, wproj, m2, m2h);
  gemm_bt<true, true><<<dim3(32, 18), 256, 0, stream>>>(xb, wqkv, bq, qkvb, vT2, 4096, 2304, 768);
  if (MS == 2) {
    attn_kernel<2><<<512, 256, 0, stream>>>(qkvb, vT2, m2h, Opart, Lpart);
    merge_kernel<2><<<1536, 256, 0, stream>>>(Opart, Lpart, aout);
  } else {
    attn_kernel<1><<<256, 256, 0, stream>>>(qkvb, vT2, m2h, aout, nullptr);
  }
  gemm_bt<false, false><<<dim3(32, 6), 256, 0, stream>>>(aout, wproj, bp, (float*)d_out, nullptr, 4096, 768, 768);
}